// Round 2
// baseline (303.646 us; speedup 1.0000x reference)
//
#include <hip/hip_runtime.h>

#define DI __device__ __forceinline__

typedef __attribute__((ext_vector_type(8))) __bf16 bfrag;   // MFMA A/B operand (4 VGPRs)
typedef __attribute__((ext_vector_type(4))) float f32x4;    // MFMA C/D operand
typedef __attribute__((ext_vector_type(4))) float fvec4;

static constexpr int Bb = 8, Ss = 1024, Dd = 768, Hh = 12, DKk = 64;
static constexpr int Mm = Bb * Ss;          // 8192 rows
static constexpr int BM = 128, BN = 128, BK = 32;
static constexpr int LDA = BK + 8;          // 40 bf16 -> 80B row stride, kills 8-way bank conflict

// load 8 fp32, convert to bf16, store 16B to LDS
DI void stage8(__bf16* dst, const float* src) {
    fvec4 a = *reinterpret_cast<const fvec4*>(src);
    fvec4 b = *reinterpret_cast<const fvec4*>(src + 4);
    bfrag o;
#pragma unroll
    for (int i = 0; i < 4; ++i) { o[i] = (__bf16)a[i]; o[i + 4] = (__bf16)b[i]; }
    *reinterpret_cast<bfrag*>(dst) = o;
}

// C = A(fp32 or bf16, [M x 768] K-contig) * W^T(fp32 [768 x 768] K-contig) + bias
// OUT_QKV: write bf16 into [B, H, S, 64];  else: write fp32 row-major [M x 768]
template <bool A_BF16, bool OUT_QKV>
__global__ __launch_bounds__(256) void gemm_k(const void* __restrict__ Ap,
                                              const float* __restrict__ Wp,
                                              const float* __restrict__ biasp,
                                              void* __restrict__ outp) {
    __shared__ __attribute__((aligned(16))) __bf16 As[BM][LDA];
    __shared__ __attribute__((aligned(16))) __bf16 Bs[BN][LDA];

    const int t = (int)threadIdx.x;
    const int lane = t & 63, w = t >> 6;
    const int l15 = lane & 15, lg = lane >> 4;
    const int row0 = (int)blockIdx.y * BM;
    const int col0 = (int)blockIdx.x * BN;
    const int wr = (w >> 1) * 64, wc = (w & 1) * 64;  // 2x2 wave grid, 64x64 per wave
    const int srow = t >> 2, scol = (t & 3) * 8;      // staging: 4 chunks of 8 per row

    f32x4 acc[4][4] = {};

    for (int k0 = 0; k0 < Dd; k0 += BK) {
        __syncthreads();
#pragma unroll
        for (int part = 0; part < 2; ++part) {
            const int ra = srow + part * 64;
            if (A_BF16) {
                const __bf16* s = (const __bf16*)Ap + (size_t)(row0 + ra) * Dd + k0 + scol;
                *reinterpret_cast<bfrag*>(&As[ra][scol]) = *reinterpret_cast<const bfrag*>(s);
            } else {
                stage8(&As[ra][scol], (const float*)Ap + (size_t)(row0 + ra) * Dd + k0 + scol);
            }
            stage8(&Bs[ra][scol], Wp + (size_t)(col0 + ra) * Dd + k0 + scol);
        }
        __syncthreads();

        bfrag af[4], bfr[4];
#pragma unroll
        for (int mi = 0; mi < 4; ++mi)
            af[mi] = *reinterpret_cast<const bfrag*>(&As[wr + mi * 16 + l15][lg * 8]);
#pragma unroll
        for (int ni = 0; ni < 4; ++ni)
            bfr[ni] = *reinterpret_cast<const bfrag*>(&Bs[wc + ni * 16 + l15][lg * 8]);
#pragma unroll
        for (int mi = 0; mi < 4; ++mi)
#pragma unroll
            for (int ni = 0; ni < 4; ++ni)
                acc[mi][ni] = __builtin_amdgcn_mfma_f32_16x16x32_bf16(af[mi], bfr[ni], acc[mi][ni], 0, 0, 0);
    }

#pragma unroll
    for (int mi = 0; mi < 4; ++mi) {
#pragma unroll
        for (int ni = 0; ni < 4; ++ni) {
            const int cg = col0 + wc + ni * 16 + l15;
            const float bv = biasp[cg];
#pragma unroll
            for (int j = 0; j < 4; ++j) {
                const int rg = row0 + wr + mi * 16 + lg * 4 + j;  // D row = (lane>>4)*4 + reg
                const float val = acc[mi][ni][j] + bv;
                if (OUT_QKV) {
                    const int bb = rg >> 10, ss = rg & 1023;
                    const int hh2 = cg >> 6, dd = cg & 63;
                    ((__bf16*)outp)[((size_t)(bb * Hh + hh2) * Ss + ss) * DKk + dd] = (__bf16)val;
                } else {
                    ((float*)outp)[(size_t)rg * Dd + cg] = val;
                }
            }
        }
    }
}

// Flash attention: grid (16 qtiles, 12 heads, 8 batch), 4 waves x 16 q-rows
__global__ __launch_bounds__(256) void attn_k(const __bf16* __restrict__ q,
                                              const __bf16* __restrict__ k,
                                              const __bf16* __restrict__ v,
                                              __bf16* __restrict__ o) {
    __shared__ __attribute__((aligned(16))) __bf16 plds[4][16][72];  // wave-private P tile, padded
    const int t = (int)threadIdx.x;
    const int lane = t & 63, w = t >> 6;
    const int l15 = lane & 15, lg = lane >> 4;
    const int qt = (int)blockIdx.x, hh = (int)blockIdx.y, bb = (int)blockIdx.z;
    const size_t bh = (size_t)(bb * Hh + hh) * Ss;
    const __bf16* qp = q + bh * DKk;
    const __bf16* kp = k + bh * DKk;
    const __bf16* vp = v + bh * DKk;
    const int qbase = qt * 64 + w * 16;

    bfrag aq[2];
#pragma unroll
    for (int ks = 0; ks < 2; ++ks)
        aq[ks] = *reinterpret_cast<const bfrag*>(qp + (size_t)(qbase + l15) * DKk + ks * 32 + lg * 8);

    float mrow[4] = {-1e30f, -1e30f, -1e30f, -1e30f};
    float lrow[4] = {0.f, 0.f, 0.f, 0.f};
    f32x4 oacc[4] = {};

    for (int kt = 0; kt < 16; ++kt) {
        const int kb = kt * 64;
        f32x4 sacc[4] = {};
#pragma unroll
        for (int n = 0; n < 4; ++n) {
#pragma unroll
            for (int ks = 0; ks < 2; ++ks) {
                const bfrag bk = *reinterpret_cast<const bfrag*>(
                    kp + (size_t)(kb + n * 16 + l15) * DKk + ks * 32 + lg * 8);
                sacc[n] = __builtin_amdgcn_mfma_f32_16x16x32_bf16(aq[ks], bk, sacc[n], 0, 0, 0);
            }
        }
        // online softmax; D layout: col(key)=l15, row(q)=lg*4+j; row stats replicated over l15
        float p[4][4];
#pragma unroll
        for (int j = 0; j < 4; ++j) {
            float mx = sacc[0][j];
#pragma unroll
            for (int n = 1; n < 4; ++n) mx = fmaxf(mx, sacc[n][j]);
            mx = fmaxf(mx, __shfl_xor(mx, 1));
            mx = fmaxf(mx, __shfl_xor(mx, 2));
            mx = fmaxf(mx, __shfl_xor(mx, 4));
            mx = fmaxf(mx, __shfl_xor(mx, 8));
            mx *= 0.125f;  // 1/sqrt(64)
            const float mnew = fmaxf(mrow[j], mx);
            const float corr = __expf(mrow[j] - mnew);
            mrow[j] = mnew;
            float rs = 0.f;
#pragma unroll
            for (int n = 0; n < 4; ++n) {
                const float pe = __expf(sacc[n][j] * 0.125f - mnew);
                p[n][j] = pe;
                rs += pe;
            }
            rs += __shfl_xor(rs, 1);
            rs += __shfl_xor(rs, 2);
            rs += __shfl_xor(rs, 4);
            rs += __shfl_xor(rs, 8);
            lrow[j] = lrow[j] * corr + rs;
#pragma unroll
            for (int dt = 0; dt < 4; ++dt) oacc[dt][j] *= corr;
        }
        // P -> wave-private LDS [q:16][key:64] (padded to 72)
#pragma unroll
        for (int j = 0; j < 4; ++j)
#pragma unroll
            for (int n = 0; n < 4; ++n)
                plds[w][lg * 4 + j][n * 16 + l15] = (__bf16)p[n][j];

        // PV: A = P (rows=q via l15, k=key), B = V[key][d]
#pragma unroll
        for (int ks = 0; ks < 2; ++ks) {
            const bfrag ap = *reinterpret_cast<const bfrag*>(&plds[w][l15][ks * 32 + lg * 8]);
#pragma unroll
            for (int dt = 0; dt < 4; ++dt) {
                bfrag bv;
#pragma unroll
                for (int e = 0; e < 8; ++e)
                    bv[e] = vp[(size_t)(kb + ks * 32 + lg * 8 + e) * DKk + dt * 16 + l15];
                oacc[dt] = __builtin_amdgcn_mfma_f32_16x16x32_bf16(ap, bv, oacc[dt], 0, 0, 0);
            }
        }
    }

#pragma unroll
    for (int dt = 0; dt < 4; ++dt) {
#pragma unroll
        for (int j = 0; j < 4; ++j) {
            const float val = oacc[dt][j] / lrow[j];
            const int qrow = qbase + lg * 4 + j;
            o[((size_t)(bb * Ss + qrow)) * Dd + hh * DKk + dt * 16 + l15] = (__bf16)val;
        }
    }
}

extern "C" void kernel_launch(void* const* d_in, const int* in_sizes, int n_in,
                              void* d_out, int out_size, void* d_ws, size_t ws_size,
                              hipStream_t stream) {
    (void)in_sizes; (void)n_in; (void)out_size; (void)ws_size;
    // dict order: key, query, value, Wk, bk, Wq, bq, Wv, bv, Wo, bo
    const float* key   = (const float*)d_in[0];
    const float* query = (const float*)d_in[1];
    const float* value = (const float*)d_in[2];
    const float* Wk = (const float*)d_in[3];
    const float* bk = (const float*)d_in[4];
    const float* Wq = (const float*)d_in[5];
    const float* bq = (const float*)d_in[6];
    const float* Wv = (const float*)d_in[7];
    const float* bvp = (const float*)d_in[8];
    const float* Wo = (const float*)d_in[9];
    const float* bo = (const float*)d_in[10];

    const size_t NELEM = (size_t)Mm * Dd;  // 6291456
    __bf16* qws = (__bf16*)d_ws;
    __bf16* kws = qws + NELEM;
    __bf16* vws = kws + NELEM;
    __bf16* aws = vws + NELEM;

    dim3 blk(256);
    dim3 gg(Dd / BN, Mm / BM);  // 6 x 64

    gemm_k<false, true><<<gg, blk, 0, stream>>>((const void*)query, Wq, bq, (void*)qws);
    gemm_k<false, true><<<gg, blk, 0, stream>>>((const void*)key,   Wk, bk, (void*)kws);
    gemm_k<false, true><<<gg, blk, 0, stream>>>((const void*)value, Wv, bvp, (void*)vws);
    attn_k<<<dim3(Ss / 64, Hh, Bb), blk, 0, stream>>>(qws, kws, vws, aws);
    gemm_k<true, false><<<gg, blk, 0, stream>>>((const void*)aws, Wo, bo, d_out);
}

// Round 3
// 237.216 us; speedup vs baseline: 1.2800x; 1.2800x over previous
//
#include <hip/hip_runtime.h>

#define DI __device__ __forceinline__

typedef __attribute__((ext_vector_type(8))) __bf16 bfrag;   // MFMA A/B operand (4 VGPRs)
typedef __attribute__((ext_vector_type(4))) float f32x4;    // MFMA C/D operand
typedef __attribute__((ext_vector_type(4))) float fvec4;

static constexpr int Bb = 8, Ss = 1024, Dd = 768, Hh = 12, DKk = 64;
static constexpr int Mm = Bb * Ss;          // 8192 rows
static constexpr int BM = 128, BN = 128, BK = 32;
static constexpr int LDA = BK + 8;          // 40 bf16 rows -> 80B stride

// load 8 fp32, convert to bf16, store 16B to LDS
DI void stage8(__bf16* dst, const float* src) {
    fvec4 a = *reinterpret_cast<const fvec4*>(src);
    fvec4 b = *reinterpret_cast<const fvec4*>(src + 4);
    bfrag o;
#pragma unroll
    for (int i = 0; i < 4; ++i) { o[i] = (__bf16)a[i]; o[i + 4] = (__bf16)b[i]; }
    *reinterpret_cast<bfrag*>(dst) = o;
}

// MODE: 0 = K-proj  (fp32 A -> bf16 [B,H,S,64])
//       1 = Q-proj  (fp32 A -> bf16 [B,H,S,64], scaled by 0.125)
//       2 = V-proj  (fp32 A -> bf16 V^T [B,H,64,S], LDS-transposed epilogue)
//       3 = out-proj(bf16 A -> fp32 [M,768])
template <int MODE>
__global__ __launch_bounds__(256) void gemm_k(const void* __restrict__ Ap,
                                              const float* __restrict__ Wp,
                                              const float* __restrict__ biasp,
                                              void* __restrict__ outp) {
    constexpr int SMB = (MODE == 2) ? (128 * 136 * 2) : (BM * LDA * 2 + BN * LDA * 2);
    __shared__ __attribute__((aligned(16))) char smem[SMB];
    auto As = reinterpret_cast<__bf16(*)[LDA]>(smem);
    auto Bs = reinterpret_cast<__bf16(*)[LDA]>(smem + (size_t)BM * LDA * 2);

    const int t = (int)threadIdx.x;
    const int lane = t & 63, w = t >> 6;
    const int l15 = lane & 15, lg = lane >> 4;
    const int row0 = (int)blockIdx.y * BM;
    const int col0 = (int)blockIdx.x * BN;
    const int wr = (w >> 1) * 64, wc = (w & 1) * 64;  // 2x2 wave grid, 64x64 per wave
    const int srow = t >> 2, scol = (t & 3) * 8;      // staging: 4 chunks of 8 per row

    f32x4 acc[4][4] = {};

    for (int k0 = 0; k0 < Dd; k0 += BK) {
        __syncthreads();
#pragma unroll
        for (int part = 0; part < 2; ++part) {
            const int ra = srow + part * 64;
            if (MODE == 3) {
                const __bf16* s = (const __bf16*)Ap + (size_t)(row0 + ra) * Dd + k0 + scol;
                *reinterpret_cast<bfrag*>(&As[ra][scol]) = *reinterpret_cast<const bfrag*>(s);
            } else {
                stage8(&As[ra][scol], (const float*)Ap + (size_t)(row0 + ra) * Dd + k0 + scol);
            }
            stage8(&Bs[ra][scol], Wp + (size_t)(col0 + ra) * Dd + k0 + scol);
        }
        __syncthreads();

        bfrag af[4], bfr[4];
#pragma unroll
        for (int mi = 0; mi < 4; ++mi)
            af[mi] = *reinterpret_cast<const bfrag*>(&As[wr + mi * 16 + l15][lg * 8]);
#pragma unroll
        for (int ni = 0; ni < 4; ++ni)
            bfr[ni] = *reinterpret_cast<const bfrag*>(&Bs[wc + ni * 16 + l15][lg * 8]);
#pragma unroll
        for (int mi = 0; mi < 4; ++mi)
#pragma unroll
            for (int ni = 0; ni < 4; ++ni)
                acc[mi][ni] = __builtin_amdgcn_mfma_f32_16x16x32_bf16(af[mi], bfr[ni], acc[mi][ni], 0, 0, 0);
    }

    if constexpr (MODE == 2) {
        // transpose epilogue: acc -> LDS T[128 d][136 pad s] -> coalesced V^T global write
        __syncthreads();
        auto T = reinterpret_cast<__bf16(*)[136]>(smem);
#pragma unroll
        for (int mi = 0; mi < 4; ++mi) {
#pragma unroll
            for (int ni = 0; ni < 4; ++ni) {
                const float bv = biasp[col0 + wc + ni * 16 + l15];
#pragma unroll
                for (int j = 0; j < 4; ++j)
                    T[wc + ni * 16 + l15][wr + mi * 16 + lg * 4 + j] = (__bf16)(acc[mi][ni][j] + bv);
            }
        }
        __syncthreads();
        const int bb2 = row0 >> 10, sb = row0 & 1023;
#pragma unroll
        for (int i = 0; i < 8; ++i) {
            const int ld = i * 16 + (t >> 4);   // local d 0..127
            const int ck = (t & 15) * 8;        // s-chunk offset
            const int head = (col0 + ld) >> 6, dd = (col0 + ld) & 63;
            __bf16* dst = (__bf16*)outp + ((size_t)(bb2 * Hh + head) * DKk + dd) * Ss + sb + ck;
            *reinterpret_cast<bfrag*>(dst) = *reinterpret_cast<const bfrag*>(&T[ld][ck]);
        }
    } else {
#pragma unroll
        for (int mi = 0; mi < 4; ++mi) {
#pragma unroll
            for (int ni = 0; ni < 4; ++ni) {
                const int cg = col0 + wc + ni * 16 + l15;
                const float bv = biasp[cg];
#pragma unroll
                for (int j = 0; j < 4; ++j) {
                    const int rg = row0 + wr + mi * 16 + lg * 4 + j;
                    float val = acc[mi][ni][j] + bv;
                    if (MODE == 1) val *= 0.125f;  // fold 1/sqrt(d_k) into Q
                    if (MODE == 0 || MODE == 1) {
                        const int bb = rg >> 10, ss = rg & 1023;
                        const int hh2 = cg >> 6, dd = cg & 63;
                        ((__bf16*)outp)[((size_t)(bb * Hh + hh2) * Ss + ss) * DKk + dd] = (__bf16)val;
                    } else {  // MODE == 3
                        ((float*)outp)[(size_t)rg * Dd + cg] = val;
                    }
                }
            }
        }
    }
}

// Flash attention: grid (16 qtiles, 12 heads, 8 batch), 4 waves x 16 q-rows.
// K tile + V^T tile staged in LDS (shared across waves); Q pre-scaled by 0.125.
__global__ __launch_bounds__(256) void attn_k(const __bf16* __restrict__ q,
                                              const __bf16* __restrict__ k,
                                              const __bf16* __restrict__ vt,
                                              __bf16* __restrict__ o) {
    __shared__ __attribute__((aligned(16))) __bf16 Ks[64][72];   // [key][d]
    __shared__ __attribute__((aligned(16))) __bf16 Vt[64][72];   // [d][key]
    __shared__ __attribute__((aligned(16))) __bf16 plds[4][16][72];
    const int t = (int)threadIdx.x;
    const int lane = t & 63, w = t >> 6;
    const int l15 = lane & 15, lg = lane >> 4;
    const int qt = (int)blockIdx.x, hh = (int)blockIdx.y, bb = (int)blockIdx.z;
    const size_t bh = (size_t)(bb * Hh + hh) * Ss;
    const __bf16* qp = q + bh * DKk;
    const __bf16* kp = k + bh * DKk;
    const __bf16* vtp = vt + bh * DKk;  // V^T: [64 d][1024 s]
    const int qbase = qt * 64 + w * 16;
    const int srow = t >> 3, sc = (t & 7) * 8;  // staging coords

    bfrag aq[2];
#pragma unroll
    for (int ks = 0; ks < 2; ++ks)
        aq[ks] = *reinterpret_cast<const bfrag*>(qp + (size_t)(qbase + l15) * DKk + ks * 32 + lg * 8);

    float mrow[4] = {-1e30f, -1e30f, -1e30f, -1e30f};
    float lrow[4] = {0.f, 0.f, 0.f, 0.f};
    f32x4 oacc[4] = {};

    for (int kt = 0; kt < 16; ++kt) {
        const int kb = kt * 64;
        __syncthreads();
#pragma unroll
        for (int p = 0; p < 2; ++p) {
            const int r = srow + p * 32;
            *reinterpret_cast<bfrag*>(&Ks[r][sc]) =
                *reinterpret_cast<const bfrag*>(kp + (size_t)(kb + r) * DKk + sc);
            *reinterpret_cast<bfrag*>(&Vt[r][sc]) =
                *reinterpret_cast<const bfrag*>(vtp + (size_t)r * Ss + kb + sc);
        }
        __syncthreads();

        f32x4 sacc[4] = {};
#pragma unroll
        for (int n = 0; n < 4; ++n) {
#pragma unroll
            for (int ks = 0; ks < 2; ++ks) {
                const bfrag bk = *reinterpret_cast<const bfrag*>(&Ks[n * 16 + l15][ks * 32 + lg * 8]);
                sacc[n] = __builtin_amdgcn_mfma_f32_16x16x32_bf16(aq[ks], bk, sacc[n], 0, 0, 0);
            }
        }
        // online softmax (Q pre-scaled); D layout: col(key)=l15, row(q)=lg*4+j
        float p[4][4];
#pragma unroll
        for (int j = 0; j < 4; ++j) {
            float mx = sacc[0][j];
#pragma unroll
            for (int n = 1; n < 4; ++n) mx = fmaxf(mx, sacc[n][j]);
            mx = fmaxf(mx, __shfl_xor(mx, 1));
            mx = fmaxf(mx, __shfl_xor(mx, 2));
            mx = fmaxf(mx, __shfl_xor(mx, 4));
            mx = fmaxf(mx, __shfl_xor(mx, 8));
            const float mnew = fmaxf(mrow[j], mx);
            const float corr = __expf(mrow[j] - mnew);
            mrow[j] = mnew;
            float rs = 0.f;
#pragma unroll
            for (int n = 0; n < 4; ++n) {
                const float pe = __expf(sacc[n][j] - mnew);
                p[n][j] = pe;
                rs += pe;
            }
            rs += __shfl_xor(rs, 1);
            rs += __shfl_xor(rs, 2);
            rs += __shfl_xor(rs, 4);
            rs += __shfl_xor(rs, 8);
            lrow[j] = lrow[j] * corr + rs;
#pragma unroll
            for (int dt = 0; dt < 4; ++dt) oacc[dt][j] *= corr;
        }
        // P -> wave-private LDS [q:16][key:64]
#pragma unroll
        for (int j = 0; j < 4; ++j)
#pragma unroll
            for (int n = 0; n < 4; ++n)
                plds[w][lg * 4 + j][n * 16 + l15] = (__bf16)p[n][j];

        // PV: A = P (row=q via l15, k=key), B = V^T tile in LDS
#pragma unroll
        for (int ks = 0; ks < 2; ++ks) {
            const bfrag ap = *reinterpret_cast<const bfrag*>(&plds[w][l15][ks * 32 + lg * 8]);
#pragma unroll
            for (int dt = 0; dt < 4; ++dt) {
                const bfrag bv = *reinterpret_cast<const bfrag*>(&Vt[dt * 16 + l15][ks * 32 + lg * 8]);
                oacc[dt] = __builtin_amdgcn_mfma_f32_16x16x32_bf16(ap, bv, oacc[dt], 0, 0, 0);
            }
        }
    }

#pragma unroll
    for (int dt = 0; dt < 4; ++dt) {
#pragma unroll
        for (int j = 0; j < 4; ++j) {
            const float val = oacc[dt][j] / lrow[j];
            const int qrow = qbase + lg * 4 + j;
            o[((size_t)(bb * Ss + qrow)) * Dd + hh * DKk + dt * 16 + l15] = (__bf16)val;
        }
    }
}

extern "C" void kernel_launch(void* const* d_in, const int* in_sizes, int n_in,
                              void* d_out, int out_size, void* d_ws, size_t ws_size,
                              hipStream_t stream) {
    (void)in_sizes; (void)n_in; (void)out_size; (void)ws_size;
    // dict order: key, query, value, Wk, bk, Wq, bq, Wv, bv, Wo, bo
    const float* key   = (const float*)d_in[0];
    const float* query = (const float*)d_in[1];
    const float* value = (const float*)d_in[2];
    const float* Wk = (const float*)d_in[3];
    const float* bk = (const float*)d_in[4];
    const float* Wq = (const float*)d_in[5];
    const float* bq = (const float*)d_in[6];
    const float* Wv = (const float*)d_in[7];
    const float* bvp = (const float*)d_in[8];
    const float* Wo = (const float*)d_in[9];
    const float* bo = (const float*)d_in[10];

    const size_t NELEM = (size_t)Mm * Dd;  // 6291456
    __bf16* qws  = (__bf16*)d_ws;
    __bf16* kws  = qws + NELEM;
    __bf16* vtws = kws + NELEM;   // V^T layout [B,H,64,S]
    __bf16* aws  = vtws + NELEM;

    dim3 blk(256);
    dim3 gg(Dd / BN, Mm / BM);  // 6 x 64

    gemm_k<1><<<gg, blk, 0, stream>>>((const void*)query, Wq, bq, (void*)qws);
    gemm_k<0><<<gg, blk, 0, stream>>>((const void*)key,   Wk, bk, (void*)kws);
    gemm_k<2><<<gg, blk, 0, stream>>>((const void*)value, Wv, bvp, (void*)vtws);
    attn_k<<<dim3(Ss / 64, Hh, Bb), blk, 0, stream>>>(qws, kws, vtws, aws);
    gemm_k<3><<<gg, blk, 0, stream>>>((const void*)aws, Wo, bo, d_out);
}